// Round 5
// baseline (161.532 us; speedup 1.0000x reference)
//
#include <hip/hip_runtime.h>

// MMD loss: source(4096x256 f32), target(4096x256 f32) -> scalar f32.
// memset(32B) + 2 kernels:
//   prep      : bf16 cast into FRAGMENT-MAJOR packed layout
//               totp[panel=row/16][kq=k/8][r=row%16][8 bf16]
//               + fp32 row norms sq[8192] + column partials colp[256][256];
//               last block (fence+ticket) reduces colp/sq -> c = log2e/(16*bw)
//   mmd_tiles : triangular 128x128 tiles of T*T^T. NO LDS, NO barriers in the
//               K-loop: each MFMA fragment is ONE coalesced 1KB
//               global_load_dwordx4 from the packed layout (L1/L2-resident),
//               register double-buffered; 1-exp2 epilogue; fence+ticket
//               last-block reduce -> d_out
#define N_TOT 8192
#define NB    4096
#define DDIM  256
#define NTILE 64
#define NBLK  (NTILE * (NTILE + 1) / 2)   // 2080
#define PREP_BLKS 256
#define ROWS_PB   (N_TOT / PREP_BLKS)     // 32 rows/block, 8 per wave

typedef __bf16 bf16x8 __attribute__((ext_vector_type(8)));
typedef float  f32x4  __attribute__((ext_vector_type(4)));

__device__ inline unsigned short f2bf_rne(float x) {
    unsigned int u = __float_as_uint(x);
    unsigned int r = (u + 0x7fffu + ((u >> 16) & 1u)) >> 16;
    return (unsigned short)r;
}

// ws layout (floats): [2]=c, [3]=mmd ticket(u32), [4]=prep ticket(u32),
// [512..8703]=sq[8192], [16384..18463]=part[2080], [32768..98303]=colp[256*256];
// byte 524288..: packed bf16 totp (4 MB)

__global__ __launch_bounds__(256) void prep(const float* __restrict__ src,
                                            const float* __restrict__ tgt,
                                            float* __restrict__ sq,
                                            unsigned short* __restrict__ totp,
                                            float* __restrict__ colp,
                                            float* __restrict__ wsf) {
    __shared__ float cs[4 * 256];
    __shared__ int plast;
    int t = threadIdx.x, w = t >> 6, lane = t & 63;
    int row0 = blockIdx.x * ROWS_PB + w * (ROWS_PB / 4);
    float4 csum = {0.f, 0.f, 0.f, 0.f};
    #pragma unroll
    for (int r = 0; r < ROWS_PB / 4; ++r) {
        int row = row0 + r;
        const float* rp = (row < NB) ? (src + (size_t)row * DDIM)
                                     : (tgt + (size_t)(row - NB) * DDIM);
        float4 v = ((const float4*)rp)[lane];
        ushort4 o;
        o.x = f2bf_rne(v.x); o.y = f2bf_rne(v.y);
        o.z = f2bf_rne(v.z); o.w = f2bf_rne(v.w);
        // packed: ((row>>4)*32 + (lane>>1))*128 + (row&15)*8 + (lane&1)*4
        size_t pidx = (size_t)(row >> 4) * 4096 + (lane >> 1) * 128
                    + (row & 15) * 8 + (lane & 1) * 4;
        *(ushort4*)(totp + pidx) = o;
        float s = v.x*v.x + v.y*v.y + v.z*v.z + v.w*v.w;
        #pragma unroll
        for (int off = 32; off > 0; off >>= 1) s += __shfl_down(s, off);
        if (lane == 0) sq[row] = s;
        csum.x += v.x; csum.y += v.y; csum.z += v.z; csum.w += v.w;
    }
    cs[w * 256 + lane * 4 + 0] = csum.x;
    cs[w * 256 + lane * 4 + 1] = csum.y;
    cs[w * 256 + lane * 4 + 2] = csum.z;
    cs[w * 256 + lane * 4 + 3] = csum.w;
    __syncthreads();
    colp[blockIdx.x * 256 + t] = (cs[t] + cs[256 + t]) + (cs[512 + t] + cs[768 + t]);
    __threadfence();
    if (t == 0) {
        unsigned int old = atomicAdd((unsigned int*)&wsf[4], 1u);
        plast = (old == PREP_BLKS - 1) ? 1 : 0;
    }
    __syncthreads();
    if (!plast) return;
    __threadfence();
    // reduce column partials -> ||s||^2 ; sum sq -> S1 ; store c
    float a[8];
    #pragma unroll
    for (int u = 0; u < 8; ++u) a[u] = 0.f;
    for (int b = 0; b < PREP_BLKS; b += 8) {
        #pragma unroll
        for (int u = 0; u < 8; ++u) a[u] += colp[(b + u) * 256 + t];
    }
    float sv = ((a[0] + a[1]) + (a[2] + a[3])) + ((a[4] + a[5]) + (a[6] + a[7]));
    float s8[8];
    #pragma unroll
    for (int u = 0; u < 8; ++u) s8[u] = 0.f;
    for (int i = 0; i < 32; i += 8) {
        #pragma unroll
        for (int u = 0; u < 8; ++u) s8[u] += sq[(i + u) * 256 + t];
    }
    float s1 = ((s8[0] + s8[1]) + (s8[2] + s8[3])) + ((s8[4] + s8[5]) + (s8[6] + s8[7]));
    float v2 = sv * sv;
    #pragma unroll
    for (int off = 32; off > 0; off >>= 1) {
        s1 += __shfl_down(s1, off);
        v2 += __shfl_down(v2, off);
    }
    if (lane == 0) { cs[w] = s1; cs[8 + w] = v2; }
    __syncthreads();
    if (t == 0) {
        float S1   = cs[0] + cs[1] + cs[2] + cs[3];
        float sdot = cs[8] + cs[9] + cs[10] + cs[11];
        float bw_sum = 2.0f * (float)N_TOT * S1 - 2.0f * sdot;
        double denom = (double)N_TOT * (double)N_TOT - (double)N_TOT;
        float bandwidth = (float)((double)bw_sum / denom) * 0.25f;
        wsf[2] = (1.0f / bandwidth) * 0.0625f * 1.44269504f;  // c = log2e/(16*bw)
    }
}

__global__ __launch_bounds__(256) void mmd_tiles(const unsigned short* __restrict__ totp,
                                                 const float* __restrict__ sq,
                                                 float* __restrict__ wsf,
                                                 float* __restrict__ part,
                                                 float* __restrict__ out) {
    __shared__ float redf[4];
    __shared__ int amlast;

    // decode upper-triangular (ti, tj) from 1-D block index
    int idx = blockIdx.x;
    int ti = (int)((129.0f - sqrtf(16641.0f - 8.0f * (float)idx)) * 0.5f);
    if (ti > 63) ti = 63;
    if (ti < 0)  ti = 0;
    while ((ti * (129 - ti)) / 2 > idx) --ti;
    while (((ti + 1) * (128 - ti)) / 2 <= idx) ++ti;
    int tj = ti + idx - (ti * (129 - ti)) / 2;

    int t = threadIdx.x;
    int wid = t >> 6, lane = t & 63;
    int rl = lane & 15, q = lane >> 4;
    int gi0 = ti * 128, gj0 = tj * 128;
    int ia = (wid >> 1) * 64, jb = (wid & 1) * 64;

    float c = wsf[2];

    // fragment base pointers: panel stride 4096 shorts, k-step stride 512 shorts
    const unsigned short* pa[4];
    const unsigned short* pb[4];
    int pA0 = (gi0 + ia) >> 4, pB0 = (gj0 + jb) >> 4;
    #pragma unroll
    for (int m = 0; m < 4; ++m) {
        pa[m] = totp + (size_t)(pA0 + m) * 4096 + lane * 8;
        pb[m] = totp + (size_t)(pB0 + m) * 4096 + lane * 8;
    }

    f32x4 acc[4][4];
    #pragma unroll
    for (int m = 0; m < 4; ++m)
        #pragma unroll
        for (int n = 0; n < 4; ++n) acc[m][n] = (f32x4){0.f, 0.f, 0.f, 0.f};

    bf16x8 av[2][4], bv[2][4];
    #pragma unroll
    for (int m = 0; m < 4; ++m) {
        av[0][m] = *(const bf16x8*)(pa[m]);
        bv[0][m] = *(const bf16x8*)(pb[m]);
    }
    #pragma unroll
    for (int s = 0; s < 8; ++s) {
        const int cur = s & 1, nxt = cur ^ 1;
        if (s < 7) {
            const int so = (s + 1) * 512;
            #pragma unroll
            for (int m = 0; m < 4; ++m) {
                av[nxt][m] = *(const bf16x8*)(pa[m] + so);
                bv[nxt][m] = *(const bf16x8*)(pb[m] + so);
            }
        }
        #pragma unroll
        for (int m = 0; m < 4; ++m)
            #pragma unroll
            for (int n = 0; n < 4; ++n)
                acc[m][n] = __builtin_amdgcn_mfma_f32_16x16x32_bf16(av[cur][m], bv[cur][n], acc[m][n], 0, 0, 0);
    }

    // epilogue: x = (2*acc - sqi - sqj)*c ; e1=2^x ; sum e1+e1^2+e1^4+e1^8+e1^16
    float tc = 2.0f * c;
    float local = 0.f;
    #pragma unroll
    for (int m = 0; m < 4; ++m) {
        f32x4 sqi = *(const f32x4*)(sq + gi0 + ia + m * 16 + q * 4);
        f32x4 ai;
        ai[0] = sqi[0] * c; ai[1] = sqi[1] * c; ai[2] = sqi[2] * c; ai[3] = sqi[3] * c;
        #pragma unroll
        for (int n = 0; n < 4; ++n) {
            float bj = sq[gj0 + jb + n * 16 + rl] * c;
            #pragma unroll
            for (int e = 0; e < 4; ++e) {
                float x  = __builtin_fmaf(acc[m][n][e], tc, -(ai[e] + bj));
                float e1 = __builtin_amdgcn_exp2f(x);
                float e2 = e1 * e1, e4 = e2 * e2, e8 = e4 * e4;
                local += ((e1 + e2) + (e4 + e8)) + e8 * e8;
            }
        }
    }
    #pragma unroll
    for (int off = 32; off > 0; off >>= 1) local += __shfl_down(local, off);
    if (lane == 0) redf[wid] = local;
    __syncthreads();
    if (t == 0) {
        float tot = redf[0] + redf[1] + redf[2] + redf[3];
        float scale = (((ti < 32) == (tj < 32)) ? 1.0f : -1.0f) * ((ti == tj) ? 1.0f : 2.0f);
        part[idx] = tot * scale;
        __threadfence();
        unsigned int old = atomicAdd((unsigned int*)&wsf[3], 1u);
        amlast = (old == NBLK - 1) ? 1 : 0;
    }
    __syncthreads();
    if (amlast) {
        __threadfence();
        float s = 0.f;
        for (int i = t; i < NBLK; i += 256) s += part[i];
        #pragma unroll
        for (int off = 32; off > 0; off >>= 1) s += __shfl_down(s, off);
        if (lane == 0) redf[wid] = s;
        __syncthreads();
        if (t == 0)
            out[0] = (redf[0] + redf[1] + redf[2] + redf[3]) * (1.0f / ((float)NB * (float)NB));
    }
}

extern "C" void kernel_launch(void* const* d_in, const int* in_sizes, int n_in,
                              void* d_out, int out_size, void* d_ws, size_t ws_size,
                              hipStream_t stream) {
    const float* src = (const float*)d_in[0];
    const float* tgt = (const float*)d_in[1];
    float* wsf  = (float*)d_ws;
    float* sq   = wsf + 512;
    float* part = wsf + 16384;
    float* colp = wsf + 32768;
    unsigned short* totp = (unsigned short*)((char*)d_ws + 524288);

    hipMemsetAsync(d_ws, 0, 32, stream);   // prep + mmd tickets
    prep<<<PREP_BLKS, 256, 0, stream>>>(src, tgt, sq, totp, colp, wsf);
    mmd_tiles<<<NBLK, 256, 0, stream>>>(totp, sq, wsf, part, (float*)d_out);
}

// Round 6
// 108.717 us; speedup vs baseline: 1.4858x; 1.4858x over previous
//
#include <hip/hip_runtime.h>

// MMD loss: source(4096x256 f32), target(4096x256 f32) -> scalar f32.
// 4 dispatches, NO device-scope fences/tickets/atomics anywhere:
//   prep        : coalesced read of src/tgt, bf16 cast -> LDS bounce ->
//                 fully-coalesced packed fragment-major writes
//                 totp[panel=row/16][kq=k/8][r=row%16][8 bf16];
//                 fp32 row norms sq[8192]; per-block column partials colp
//   finalize_bw : 1 block: reduce colp + sq -> c = log2e/(16*bandwidth)
//   mmd_tiles   : triangular 128x128 tiles of T*T^T; no LDS, no barriers in
//                 K-loop: fragment = one coalesced 1KB global_load_dwordx4,
//                 register double-buffered; 1-exp2 epilogue; part[idx] store
//   write_out   : 1 block: sum part[2080] -> d_out
#define N_TOT 8192
#define NB    4096
#define DDIM  256
#define NTILE 64
#define NBLK  (NTILE * (NTILE + 1) / 2)   // 2080
#define PREP_BLKS 128                     // 4 waves/block, 1 panel(16 rows)/wave

typedef __bf16 bf16x8 __attribute__((ext_vector_type(8)));
typedef float  f32x4  __attribute__((ext_vector_type(4)));

__device__ inline unsigned short f2bf_rne(float x) {
    unsigned int u = __float_as_uint(x);
    unsigned int r = (u + 0x7fffu + ((u >> 16) & 1u)) >> 16;
    return (unsigned short)r;
}

// ws layout (floats): [2]=c, [512..8703]=sq[8192], [16384..18463]=part[2080],
// [32768..65535]=colp[128*256]; byte 524288..: packed bf16 totp (4 MB)

__global__ __launch_bounds__(256) void prep(const float* __restrict__ src,
                                            const float* __restrict__ tgt,
                                            float* __restrict__ sq,
                                            unsigned short* __restrict__ totp,
                                            float* __restrict__ colp) {
    // per-wave panel buffer: 32 kq-slabs x 136 shorts (8-short pad: bank-spread)
    __shared__ unsigned short pbuf[4][32 * 136];
    __shared__ float cs[4 * 256];
    int t = threadIdx.x, w = t >> 6, lane = t & 63;
    int panel = blockIdx.x * 4 + w;          // 512 panels of 16 rows
    int row0  = panel * 16;

    float4 csum = {0.f, 0.f, 0.f, 0.f};
    int ls_base = (lane >> 1) * 136 + (lane & 1) * 4;   // kq-slab + e-offset
    #pragma unroll
    for (int r = 0; r < 16; ++r) {
        int row = row0 + r;
        const float* rp = (row < NB) ? (src + (size_t)row * DDIM)
                                     : (tgt + (size_t)(row - NB) * DDIM);
        float4 v = ((const float4*)rp)[lane];
        ushort4 o;
        o.x = f2bf_rne(v.x); o.y = f2bf_rne(v.y);
        o.z = f2bf_rne(v.z); o.w = f2bf_rne(v.w);
        *(ushort4*)&pbuf[w][ls_base + r * 8] = o;
        float s = v.x*v.x + v.y*v.y + v.z*v.z + v.w*v.w;
        #pragma unroll
        for (int off = 32; off > 0; off >>= 1) s += __shfl_down(s, off);
        if (lane == 0) sq[row] = s;
        csum.x += v.x; csum.y += v.y; csum.z += v.z; csum.w += v.w;
    }
    // coalesced packed writeback: 16 x 512B stores per wave
    #pragma unroll
    for (int it = 0; it < 16; ++it) {
        int g  = it * 256 + lane * 4;            // linear packed index in panel
        int kq = g >> 7, wi = g & 127;
        ushort4 o = *(const ushort4*)&pbuf[w][kq * 136 + wi];
        *(ushort4*)(totp + (size_t)panel * 4096 + g) = o;
    }
    __syncthreads();                              // before reusing LDS region
    cs[w * 256 + lane * 4 + 0] = csum.x;
    cs[w * 256 + lane * 4 + 1] = csum.y;
    cs[w * 256 + lane * 4 + 2] = csum.z;
    cs[w * 256 + lane * 4 + 3] = csum.w;
    __syncthreads();
    colp[blockIdx.x * 256 + t] = (cs[t] + cs[256 + t]) + (cs[512 + t] + cs[768 + t]);
}

__global__ void finalize_bw(const float* __restrict__ colp,
                            const float* __restrict__ sq,
                            float* __restrict__ wsf) {
    __shared__ float redA[4], redB[4];
    int t = threadIdx.x, lane = t & 63, w = t >> 6;
    float a[8];
    #pragma unroll
    for (int u = 0; u < 8; ++u) a[u] = 0.f;
    for (int b = 0; b < PREP_BLKS; b += 8) {
        #pragma unroll
        for (int u = 0; u < 8; ++u) a[u] += colp[(b + u) * 256 + t];
    }
    float sv = ((a[0] + a[1]) + (a[2] + a[3])) + ((a[4] + a[5]) + (a[6] + a[7]));
    float s8[8];
    #pragma unroll
    for (int u = 0; u < 8; ++u) s8[u] = 0.f;
    for (int i = 0; i < 32; i += 8) {
        #pragma unroll
        for (int u = 0; u < 8; ++u) s8[u] += sq[(i + u) * 256 + t];
    }
    float s1 = ((s8[0] + s8[1]) + (s8[2] + s8[3])) + ((s8[4] + s8[5]) + (s8[6] + s8[7]));
    float v2 = sv * sv;
    #pragma unroll
    for (int off = 32; off > 0; off >>= 1) {
        s1 += __shfl_down(s1, off);
        v2 += __shfl_down(v2, off);
    }
    if (lane == 0) { redA[w] = s1; redB[w] = v2; }
    __syncthreads();
    if (t == 0) {
        float S1   = redA[0] + redA[1] + redA[2] + redA[3];
        float sdot = redB[0] + redB[1] + redB[2] + redB[3];
        float bw_sum = 2.0f * (float)N_TOT * S1 - 2.0f * sdot;
        double denom = (double)N_TOT * (double)N_TOT - (double)N_TOT;
        float bandwidth = (float)((double)bw_sum / denom) * 0.25f;
        wsf[2] = (1.0f / bandwidth) * 0.0625f * 1.44269504f;  // c = log2e/(16*bw)
    }
}

__global__ __launch_bounds__(256) void mmd_tiles(const unsigned short* __restrict__ totp,
                                                 const float* __restrict__ sq,
                                                 const float* __restrict__ wsf,
                                                 float* __restrict__ part) {
    __shared__ float redf[4];

    // decode upper-triangular (ti, tj) from 1-D block index
    int idx = blockIdx.x;
    int ti = (int)((129.0f - sqrtf(16641.0f - 8.0f * (float)idx)) * 0.5f);
    if (ti > 63) ti = 63;
    if (ti < 0)  ti = 0;
    while ((ti * (129 - ti)) / 2 > idx) --ti;
    while (((ti + 1) * (128 - ti)) / 2 <= idx) ++ti;
    int tj = ti + idx - (ti * (129 - ti)) / 2;

    int t = threadIdx.x;
    int wid = t >> 6, lane = t & 63;
    int rl = lane & 15, q = lane >> 4;
    int gi0 = ti * 128, gj0 = tj * 128;
    int ia = (wid >> 1) * 64, jb = (wid & 1) * 64;

    float c = wsf[2];

    // fragment pointers: panel stride 4096 shorts, k-step stride 512 shorts
    const unsigned short* pa[4];
    const unsigned short* pb[4];
    int pA0 = (gi0 + ia) >> 4, pB0 = (gj0 + jb) >> 4;
    #pragma unroll
    for (int m = 0; m < 4; ++m) {
        pa[m] = totp + (size_t)(pA0 + m) * 4096 + lane * 8;
        pb[m] = totp + (size_t)(pB0 + m) * 4096 + lane * 8;
    }

    f32x4 acc[4][4];
    #pragma unroll
    for (int m = 0; m < 4; ++m)
        #pragma unroll
        for (int n = 0; n < 4; ++n) acc[m][n] = (f32x4){0.f, 0.f, 0.f, 0.f};

    bf16x8 av[2][4], bv[2][4];
    #pragma unroll
    for (int m = 0; m < 4; ++m) {
        av[0][m] = *(const bf16x8*)(pa[m]);
        bv[0][m] = *(const bf16x8*)(pb[m]);
    }
    #pragma unroll
    for (int s = 0; s < 8; ++s) {
        const int cur = s & 1, nxt = cur ^ 1;
        if (s < 7) {
            const int so = (s + 1) * 512;
            #pragma unroll
            for (int m = 0; m < 4; ++m) {
                av[nxt][m] = *(const bf16x8*)(pa[m] + so);
                bv[nxt][m] = *(const bf16x8*)(pb[m] + so);
            }
        }
        #pragma unroll
        for (int m = 0; m < 4; ++m)
            #pragma unroll
            for (int n = 0; n < 4; ++n)
                acc[m][n] = __builtin_amdgcn_mfma_f32_16x16x32_bf16(av[cur][m], bv[cur][n], acc[m][n], 0, 0, 0);
    }

    // epilogue: x = (2*acc - sqi - sqj)*c ; e1=2^x ; sum e1+e1^2+e1^4+e1^8+e1^16
    float tc = 2.0f * c;
    float local = 0.f;
    #pragma unroll
    for (int m = 0; m < 4; ++m) {
        f32x4 sqi = *(const f32x4*)(sq + gi0 + ia + m * 16 + q * 4);
        f32x4 ai;
        ai[0] = sqi[0] * c; ai[1] = sqi[1] * c; ai[2] = sqi[2] * c; ai[3] = sqi[3] * c;
        #pragma unroll
        for (int n = 0; n < 4; ++n) {
            float bj = sq[gj0 + jb + n * 16 + rl] * c;
            #pragma unroll
            for (int e = 0; e < 4; ++e) {
                float x  = __builtin_fmaf(acc[m][n][e], tc, -(ai[e] + bj));
                float e1 = __builtin_amdgcn_exp2f(x);
                float e2 = e1 * e1, e4 = e2 * e2, e8 = e4 * e4;
                local += ((e1 + e2) + (e4 + e8)) + e8 * e8;
            }
        }
    }
    #pragma unroll
    for (int off = 32; off > 0; off >>= 1) local += __shfl_down(local, off);
    if (lane == 0) redf[wid] = local;
    __syncthreads();
    if (t == 0) {
        float tot = redf[0] + redf[1] + redf[2] + redf[3];
        float scale = (((ti < 32) == (tj < 32)) ? 1.0f : -1.0f) * ((ti == tj) ? 1.0f : 2.0f);
        part[idx] = tot * scale;
    }
}

__global__ void write_out(const float* __restrict__ part, float* __restrict__ out) {
    __shared__ float red[4];
    int t = threadIdx.x, lane = t & 63, w = t >> 6;
    float s = 0.f;
    for (int i = t; i < NBLK; i += 256) s += part[i];
    #pragma unroll
    for (int off = 32; off > 0; off >>= 1) s += __shfl_down(s, off);
    if (lane == 0) red[w] = s;
    __syncthreads();
    if (t == 0)
        out[0] = (red[0] + red[1] + red[2] + red[3]) * (1.0f / ((float)NB * (float)NB));
}

extern "C" void kernel_launch(void* const* d_in, const int* in_sizes, int n_in,
                              void* d_out, int out_size, void* d_ws, size_t ws_size,
                              hipStream_t stream) {
    const float* src = (const float*)d_in[0];
    const float* tgt = (const float*)d_in[1];
    float* wsf  = (float*)d_ws;
    float* sq   = wsf + 512;
    float* part = wsf + 16384;
    float* colp = wsf + 32768;
    unsigned short* totp = (unsigned short*)((char*)d_ws + 524288);

    prep<<<PREP_BLKS, 256, 0, stream>>>(src, tgt, sq, totp, colp);
    finalize_bw<<<1, 256, 0, stream>>>(colp, sq, wsf);
    mmd_tiles<<<NBLK, 256, 0, stream>>>(totp, sq, wsf, part);
    write_out<<<1, 256, 0, stream>>>(part, (float*)d_out);
}